// Round 2
// baseline (305.797 us; speedup 1.0000x reference)
//
#include <hip/hip_runtime.h>

#define DD 128
#define NP 8
#define NK 4
#define NB 65536
#define COLS 64      // batch columns per block
#define PSTR 37      // odd stride for 36-float partial rows (conflict-free)

// ---------------------------------------------------------------------------
// K1: attention weights + weighted combine + relu + +q + LN1 stats.
// 256 threads = 64 columns x 4 d-quarters (quarter == wave). Dot-product
// partials (4 qd + 32 kd) reduced across waves via padded LDS.
// ---------------------------------------------------------------------------
__global__ __launch_bounds__(256) void k1_attn_combine(
    const float* __restrict__ q, const float* __restrict__ keys,
    const float* __restrict__ A, float* __restrict__ y,
    float* __restrict__ mu_o, float* __restrict__ rs_o)
{
    __shared__ float lds[4 * COLS * PSTR];   // 37888 B -> 4 blocks/CU
    const int col = threadIdx.x & 63;
    const int dg  = __builtin_amdgcn_readfirstlane(threadIdx.x >> 6); // wave id
    const int b   = blockIdx.x * COLS + col;
    const int dbase = dg * 32;

    // ---- pass 1: partial dots over this wave's 32 d's --------------------
    float qd[NK] = {0.f, 0.f, 0.f, 0.f};
    float kd[NP][NK];
    #pragma unroll
    for (int n = 0; n < NP; ++n)
        #pragma unroll
        for (int k = 0; k < NK; ++k) kd[n][k] = 0.f;

    #pragma unroll 4
    for (int dd = 0; dd < 32; ++dd) {
        const int d = dbase + dd;                       // wave-uniform
        const float4 at = *(const float4*)(A + d * NK);        // s_load
        const float4 ab = *(const float4*)(A + (DD + d) * NK); // s_load
        const float qv = q[d * NB + b];
        qd[0] += qv * at.x; qd[1] += qv * at.y;
        qd[2] += qv * at.z; qd[3] += qv * at.w;
        #pragma unroll
        for (int n = 0; n < NP; ++n) {
            const float kv = keys[(n * DD + d) * NB + b];
            kd[n][0] += kv * ab.x; kd[n][1] += kv * ab.y;
            kd[n][2] += kv * ab.z; kd[n][3] += kv * ab.w;
        }
    }

    // ---- cross-wave reduce of the 36 partials ----------------------------
    {
        float* my = &lds[(dg * COLS + col) * PSTR];
        #pragma unroll
        for (int k = 0; k < NK; ++k) my[k] = qd[k];
        #pragma unroll
        for (int n = 0; n < NP; ++n)
            #pragma unroll
            for (int k = 0; k < NK; ++k) my[4 + n * NK + k] = kd[n][k];
    }
    __syncthreads();
    // phase B: this wave reduces 9 of the 36 sums into the dg0 region
    #pragma unroll
    for (int ii = 0; ii < 9; ++ii) {
        const int i = dg * 9 + ii;
        float s = lds[(0 * COLS + col) * PSTR + i]
                + lds[(1 * COLS + col) * PSTR + i]
                + lds[(2 * COLS + col) * PSTR + i]
                + lds[(3 * COLS + col) * PSTR + i];
        lds[col * PSTR + i] = s;   // self-RAW only: safe
    }
    __syncthreads();

    // ---- phase C: every thread reads the 36 sums, softmax over n ---------
    float z[NP][NK];
    {
        float qs[NK];
        #pragma unroll
        for (int k = 0; k < NK; ++k) qs[k] = lds[col * PSTR + k];
        float mx[NK] = {-3.4e38f, -3.4e38f, -3.4e38f, -3.4e38f};
        #pragma unroll
        for (int n = 0; n < NP; ++n)
            #pragma unroll
            for (int k = 0; k < NK; ++k) {
                float v = qs[k] + lds[col * PSTR + 4 + n * NK + k];
                v = (v >= 0.f) ? v : 0.01f * v;     // leaky_relu
                z[n][k] = v;
                mx[k] = fmaxf(mx[k], v);
            }
        float S[NK] = {0.f, 0.f, 0.f, 0.f};
        #pragma unroll
        for (int n = 0; n < NP; ++n)
            #pragma unroll
            for (int k = 0; k < NK; ++k) {
                const float e = __expf(z[n][k] - mx[k]);
                z[n][k] = e;
                S[k] += e;
            }
        #pragma unroll
        for (int k = 0; k < NK; ++k) S[k] = 1.f / S[k];
        #pragma unroll
        for (int n = 0; n < NP; ++n)
            z[n][0] = 0.25f * (z[n][0] * S[0] + z[n][1] * S[1] +
                               z[n][2] * S[2] + z[n][3] * S[3]);
    }
    float w[NP];
    #pragma unroll
    for (int n = 0; n < NP; ++n) w[n] = z[n][0];
    __syncthreads();   // protect lds before stats reuse

    // ---- pass 2: weighted combine + relu + residual + LN1 partials -------
    float sum = 0.f, ssq = 0.f;
    #pragma unroll 4
    for (int dd = 0; dd < 32; ++dd) {
        const int d = dbase + dd;
        float acc = 0.f;
        #pragma unroll
        for (int n = 0; n < NP; ++n) acc += w[n] * keys[(n * DD + d) * NB + b];
        const float yv = fmaxf(acc, 0.f) + q[d * NB + b];
        y[d * NB + b] = yv;
        sum += yv;
        ssq += yv * yv;
    }
    lds[(dg * COLS + col) * PSTR + 0] = sum;
    lds[(dg * COLS + col) * PSTR + 1] = ssq;
    __syncthreads();
    if (dg == 0) {
        float ts = 0.f, tq = 0.f;
        #pragma unroll
        for (int g = 0; g < 4; ++g) {
            ts += lds[(g * COLS + col) * PSTR + 0];
            tq += lds[(g * COLS + col) * PSTR + 1];
        }
        const float mu  = ts * (1.f / DD);
        const float var = tq * (1.f / DD) - mu * mu;
        mu_o[b] = mu;
        rs_o[b] = rsqrtf(var + 1e-6f);
    }
}

// ---------------------------------------------------------------------------
// K2: c = LN1(y); linear = W@c + B + c; out = LN2(linear).
// 256 threads = 64 columns x 4 j-quarters. c: 32 regs/thread. GEMM done as
// scalar-W x vector-c partials, reduced across waves via LDS in 4 chunks
// of 32 output rows. In-place over d_out (reads before barrier-guarded
// writes, per-block column ranges disjoint).
// ---------------------------------------------------------------------------
__global__ __launch_bounds__(256) void k2_post(
    const float* y, const float* __restrict__ mu_a, const float* __restrict__ rs_a,
    const float* __restrict__ g1, const float* __restrict__ b1,
    const float* __restrict__ W,  const float* __restrict__ Bv,
    const float* __restrict__ g2, const float* __restrict__ b2,
    float* out)
{
    __shared__ float partl[4 * COLS * 33];   // 33792 B
    __shared__ float redl[COLS * 133];       // 34048 B  (total 67840 -> 2 blk/CU)
    const int col = threadIdx.x & 63;
    const int dg  = __builtin_amdgcn_readfirstlane(threadIdx.x >> 6);
    const int b   = blockIdx.x * COLS + col;
    const float mu = mu_a[b], rs = rs_a[b];

    // c slice for this wave's 32 j's (registers, static indices)
    float c[32];
    #pragma unroll
    for (int jj = 0; jj < 32; ++jj) {
        const int j = dg * 32 + jj;                     // wave-uniform
        c[jj] = g1[j] * ((y[j * NB + b] - mu) * rs) + b1[j];
    }

    // GEMM: 4 chunks of 32 output rows
    for (int m = 0; m < 4; ++m) {
        float p[32];
        #pragma unroll
        for (int i = 0; i < 32; ++i) p[i] = 0.f;
        #pragma unroll 4
        for (int i = 0; i < 32; ++i) {
            const int d = m * 32 + i;                   // wave-uniform
            const float* Wr = W + d * DD + dg * 32;     // scalar base
            #pragma unroll
            for (int jj = 0; jj < 32; ++jj) p[i] += Wr[jj] * c[jj];
        }
        __syncthreads();   // previous chunk's partl reads complete
        #pragma unroll
        for (int i = 0; i < 32; ++i)
            partl[(dg * COLS + col) * 33 + i] = p[i];
        __syncthreads();
        // reduce 8 of the 32 rows of this chunk
        #pragma unroll
        for (int ii = 0; ii < 8; ++ii) {
            const int i = dg * 8 + ii;
            float s = partl[(0 * COLS + col) * 33 + i]
                    + partl[(1 * COLS + col) * 33 + i]
                    + partl[(2 * COLS + col) * 33 + i]
                    + partl[(3 * COLS + col) * 33 + i];
            redl[col * 133 + m * 32 + i] = s;
        }
    }
    __syncthreads();

    // finals for this wave's 32 output rows (d == dg*32+i matches c slice)
    float v[32];
    float psum = 0.f, pssq = 0.f;
    #pragma unroll
    for (int i = 0; i < 32; ++i) {
        const int d = dg * 32 + i;                      // wave-uniform
        const float val = redl[col * 133 + d] + Bv[d] + c[i];
        v[i] = val;
        psum += val;
        pssq += val * val;
    }
    partl[(dg * COLS + col) * 33 + 0] = psum;
    partl[(dg * COLS + col) * 33 + 1] = pssq;
    __syncthreads();
    float ts = 0.f, tq = 0.f;
    #pragma unroll
    for (int g = 0; g < 4; ++g) {
        ts += partl[(g * COLS + col) * 33 + 0];
        tq += partl[(g * COLS + col) * 33 + 1];
    }
    const float mu2 = ts * (1.f / DD);
    const float rs2 = rsqrtf(tq * (1.f / DD) - mu2 * mu2 + 1e-6f);
    #pragma unroll
    for (int i = 0; i < 32; ++i) {
        const int d = dg * 32 + i;                      // wave-uniform
        out[d * NB + b] = g2[d] * ((v[i] - mu2) * rs2) + b2[d];
    }
}

extern "C" void kernel_launch(void* const* d_in, const int* in_sizes, int n_in,
                              void* d_out, int out_size, void* d_ws, size_t ws_size,
                              hipStream_t stream)
{
    const float* q    = (const float*)d_in[0];  // [1,128,65536]
    const float* keys = (const float*)d_in[1];  // [8,128,65536]
    const float* A    = (const float*)d_in[2];  // [256,4]
    const float* g1   = (const float*)d_in[3];  // [128]
    const float* b1   = (const float*)d_in[4];  // [128]
    const float* W    = (const float*)d_in[5];  // [128,128]
    const float* Bv   = (const float*)d_in[6];  // [128,1]
    const float* g2   = (const float*)d_in[7];  // [128]
    const float* b2   = (const float*)d_in[8];  // [128]
    float* out = (float*)d_out;                 // [128,65536]

    float* mu = (float*)d_ws;                   // [65536]
    float* rs = mu + NB;                        // [65536]

    k1_attn_combine<<<NB / COLS, 256, 0, stream>>>(q, keys, A, out, mu, rs);
    k2_post<<<NB / COLS, 256, 0, stream>>>(out, mu, rs, g1, b1, W, Bv, g2, b2, out);
}

// Round 3
// 278.692 us; speedup vs baseline: 1.0973x; 1.0973x over previous
//
#include <hip/hip_runtime.h>

#define DD 128
#define NP 8
#define NK 4
#define NB 65536
#define BCOLS 32     // columns per block = 4 waves x 8 cols
#define DPG 16       // d's per thread (128 / 8 d-groups)
#define CST 136      // c_lds row stride in bf16 elems (68 dwords = 4 mod 32)

typedef __bf16 bf16x8 __attribute__((ext_vector_type(8)));
typedef float  f32x4  __attribute__((ext_vector_type(4)));

// One fused kernel: attention weights -> combine -> LN1 -> (bf16 MFMA) W@c
// -> +B +c -> LN2 -> out.  Wave layout: lane = col8*8 + dg; all per-column
// reductions are shfl_xor over lane bits 0..2.  Only 2 barriers.
__global__ __launch_bounds__(256, 5) void fused_attn(
    const float* __restrict__ q, const float* __restrict__ keys,
    const float* __restrict__ A,
    const float* __restrict__ g1, const float* __restrict__ b1,
    const float* __restrict__ W,  const float* __restrict__ Bv,
    const float* __restrict__ g2, const float* __restrict__ b2,
    float* __restrict__ out)
{
    __shared__ __align__(16) __bf16 c_l[BCOLS * CST];   // 8704 B
    __shared__ float sums2[4 * BCOLS * 2];              // 1024 B

    const int t    = threadIdx.x;
    const int lane = t & 63;
    const int wv   = t >> 6;          // wave 0..3
    const int col8 = lane >> 3;       // 0..7
    const int dg   = lane & 7;        // d-group 0..7
    const int bcol = wv * 8 + col8;   // 0..31
    const int b    = blockIdx.x * BCOLS + bcol;
    const int d0   = dg * DPG;

    // ---------------- pass 1: partial dots over this thread's 16 d's ------
    float qd[NK] = {0.f, 0.f, 0.f, 0.f};
    float kd[NP][NK];
    #pragma unroll
    for (int n = 0; n < NP; ++n)
        #pragma unroll
        for (int k = 0; k < NK; ++k) kd[n][k] = 0.f;
    float qv[DPG];                    // keep q for pass 2 (saves a re-read)

    #pragma unroll
    for (int dd = 0; dd < DPG; ++dd) {
        const int d = d0 + dd;
        const float4 at = *(const float4*)(A + d * NK);
        const float4 ab = *(const float4*)(A + (DD + d) * NK);
        const float qq = q[d * NB + b];
        qv[dd] = qq;
        qd[0] += qq * at.x; qd[1] += qq * at.y;
        qd[2] += qq * at.z; qd[3] += qq * at.w;
        #pragma unroll
        for (int n = 0; n < NP; ++n) {
            const float kv = keys[(n * DD + d) * NB + b];
            kd[n][0] += kv * ab.x; kd[n][1] += kv * ab.y;
            kd[n][2] += kv * ab.z; kd[n][3] += kv * ab.w;
        }
    }
    // ---- reduce the 36 partials across the 8 d-groups (lane bits 0..2) ---
    #pragma unroll
    for (int m = 1; m <= 4; m <<= 1) {
        #pragma unroll
        for (int k = 0; k < NK; ++k) qd[k] += __shfl_xor(qd[k], m);
        #pragma unroll
        for (int n = 0; n < NP; ++n)
            #pragma unroll
            for (int k = 0; k < NK; ++k) kd[n][k] += __shfl_xor(kd[n][k], m);
    }

    // ---- leaky_relu + softmax over n; w_n = 0.25 * sum_k softmax ---------
    float w_[NP];
    {
        float z[NP][NK];
        float mx[NK] = {-3.4e38f, -3.4e38f, -3.4e38f, -3.4e38f};
        #pragma unroll
        for (int n = 0; n < NP; ++n)
            #pragma unroll
            for (int k = 0; k < NK; ++k) {
                float v = qd[k] + kd[n][k];
                v = (v >= 0.f) ? v : 0.01f * v;
                z[n][k] = v;
                mx[k] = fmaxf(mx[k], v);
            }
        float S[NK] = {0.f, 0.f, 0.f, 0.f};
        #pragma unroll
        for (int n = 0; n < NP; ++n)
            #pragma unroll
            for (int k = 0; k < NK; ++k) {
                const float e = __expf(z[n][k] - mx[k]);
                z[n][k] = e;
                S[k] += e;
            }
        #pragma unroll
        for (int k = 0; k < NK; ++k) S[k] = 1.f / S[k];
        #pragma unroll
        for (int n = 0; n < NP; ++n)
            w_[n] = 0.25f * (z[n][0] * S[0] + z[n][1] * S[1] +
                             z[n][2] * S[2] + z[n][3] * S[3]);
    }

    // ---------------- pass 2: combine + relu + +q + LN1 -------------------
    float y[DPG];
    float s1 = 0.f, s2 = 0.f;
    #pragma unroll
    for (int dd = 0; dd < DPG; ++dd) {
        const int d = d0 + dd;
        float acc = 0.f;
        #pragma unroll
        for (int n = 0; n < NP; ++n) acc += w_[n] * keys[(n * DD + d) * NB + b];
        const float yv = fmaxf(acc, 0.f) + qv[dd];
        y[dd] = yv;
        s1 += yv;
        s2 += yv * yv;
    }
    #pragma unroll
    for (int m = 1; m <= 4; m <<= 1) {
        s1 += __shfl_xor(s1, m);
        s2 += __shfl_xor(s2, m);
    }
    const float mu = s1 * (1.f / DD);
    const float rs = rsqrtf(s2 * (1.f / DD) - mu * mu + 1e-6f);

    // c = LN1(y) -> bf16 -> LDS tile [BCOLS][CST]
    {
        __bf16 cb[DPG];
        #pragma unroll
        for (int dd = 0; dd < DPG; ++dd) {
            const int d = d0 + dd;
            cb[dd] = (__bf16)(g1[d] * ((y[dd] - mu) * rs) + b1[d]);
        }
        *(uint4*)(c_l + bcol * CST + d0)     = ((const uint4*)cb)[0];
        *(uint4*)(c_l + bcol * CST + d0 + 8) = ((const uint4*)cb)[1];
    }
    __syncthreads();   // (1) c tile complete

    // ---------------- MFMA: this wave's 32 output rows x 32 cols ----------
    // A = W rows [wv*32, wv*32+32), bf16 frags in regs straight from global.
    bf16x8 wf[2][4];
    #pragma unroll
    for (int mi = 0; mi < 2; ++mi)
        #pragma unroll
        for (int kk = 0; kk < 4; ++kk) {
            const int row = wv * 32 + mi * 16 + (lane & 15);
            const int k   = kk * 32 + (lane >> 4) * 8;
            const float4 wa = *(const float4*)(W + row * DD + k);
            const float4 wb = *(const float4*)(W + row * DD + k + 4);
            bf16x8 f;
            f[0] = (__bf16)wa.x; f[1] = (__bf16)wa.y;
            f[2] = (__bf16)wa.z; f[3] = (__bf16)wa.w;
            f[4] = (__bf16)wb.x; f[5] = (__bf16)wb.y;
            f[6] = (__bf16)wb.z; f[7] = (__bf16)wb.w;
            wf[mi][kk] = f;
        }

    f32x4 acc[2][2] = {{{0.f,0.f,0.f,0.f},{0.f,0.f,0.f,0.f}},
                       {{0.f,0.f,0.f,0.f},{0.f,0.f,0.f,0.f}}};
    #pragma unroll
    for (int kk = 0; kk < 4; ++kk) {
        const int k = kk * 32 + (lane >> 4) * 8;
        #pragma unroll
        for (int nf = 0; nf < 2; ++nf) {
            const int bc = nf * 16 + (lane & 15);
            const bf16x8 bf = *(const bf16x8*)(c_l + bc * CST + k);
            acc[0][nf] = __builtin_amdgcn_mfma_f32_16x16x32_bf16(
                wf[0][kk], bf, acc[0][nf], 0, 0, 0);
            acc[1][nf] = __builtin_amdgcn_mfma_f32_16x16x32_bf16(
                wf[1][kk], bf, acc[1][nf], 0, 0, 0);
        }
    }

    // ---------------- epilogue: v = acc + B + c;  LN2; store --------------
    // D layout: col = lane&15 (within nf), row(d) = wv*32 + mi*16 + (lane>>4)*4 + r
    float vB[2][4], vg2[2][4], vb2[2][4];
    #pragma unroll
    for (int mi = 0; mi < 2; ++mi)
        #pragma unroll
        for (int r = 0; r < 4; ++r) {
            const int d = wv * 32 + mi * 16 + (lane >> 4) * 4 + r;
            vB[mi][r]  = Bv[d];
            vg2[mi][r] = g2[d];
            vb2[mi][r] = b2[d];
        }

    float vv[2][2][4];
    float ps[2] = {0.f, 0.f}, pq[2] = {0.f, 0.f};
    #pragma unroll
    for (int nf = 0; nf < 2; ++nf) {
        const int bc = nf * 16 + (lane & 15);
        #pragma unroll
        for (int mi = 0; mi < 2; ++mi)
            #pragma unroll
            for (int r = 0; r < 4; ++r) {
                const int d = wv * 32 + mi * 16 + (lane >> 4) * 4 + r;
                const float cres = (float)c_l[bc * CST + d];
                const float v = acc[mi][nf][r] + vB[mi][r] + cres;
                vv[mi][nf][r] = v;
                ps[nf] += v;
                pq[nf] += v * v;
            }
    }
    // reduce over the 4 row-groups (lane bits 4,5) -> per-column wave sums
    #pragma unroll
    for (int nf = 0; nf < 2; ++nf) {
        ps[nf] += __shfl_xor(ps[nf], 16); ps[nf] += __shfl_xor(ps[nf], 32);
        pq[nf] += __shfl_xor(pq[nf], 16); pq[nf] += __shfl_xor(pq[nf], 32);
    }
    if (lane < 16) {
        sums2[(wv * BCOLS + lane) * 2 + 0]        = ps[0];
        sums2[(wv * BCOLS + lane) * 2 + 1]        = pq[0];
        sums2[(wv * BCOLS + 16 + lane) * 2 + 0]   = ps[1];
        sums2[(wv * BCOLS + 16 + lane) * 2 + 1]   = pq[1];
    }
    __syncthreads();   // (2) cross-wave LN2 sums ready

    #pragma unroll
    for (int nf = 0; nf < 2; ++nf) {
        const int bc = nf * 16 + (lane & 15);
        float ts = 0.f, tq = 0.f;
        #pragma unroll
        for (int g = 0; g < 4; ++g) {
            ts += sums2[(g * BCOLS + bc) * 2 + 0];
            tq += sums2[(g * BCOLS + bc) * 2 + 1];
        }
        const float mu2 = ts * (1.f / DD);
        const float rs2 = rsqrtf(tq * (1.f / DD) - mu2 * mu2 + 1e-6f);
        const int bo = blockIdx.x * BCOLS + bc;
        #pragma unroll
        for (int mi = 0; mi < 2; ++mi)
            #pragma unroll
            for (int r = 0; r < 4; ++r) {
                const int d = wv * 32 + mi * 16 + (lane >> 4) * 4 + r;
                out[d * NB + bo] =
                    vg2[mi][r] * ((vv[mi][nf][r] - mu2) * rs2) + vb2[mi][r];
            }
    }
}

extern "C" void kernel_launch(void* const* d_in, const int* in_sizes, int n_in,
                              void* d_out, int out_size, void* d_ws, size_t ws_size,
                              hipStream_t stream)
{
    const float* q    = (const float*)d_in[0];
    const float* keys = (const float*)d_in[1];
    const float* A    = (const float*)d_in[2];
    const float* g1   = (const float*)d_in[3];
    const float* b1   = (const float*)d_in[4];
    const float* W    = (const float*)d_in[5];
    const float* Bv   = (const float*)d_in[6];
    const float* g2   = (const float*)d_in[7];
    const float* b2   = (const float*)d_in[8];
    float* out = (float*)d_out;

    fused_attn<<<NB / BCOLS, 256, 0, stream>>>(q, keys, A, g1, b1, W, Bv, g2, b2, out);
}

// Round 6
// 121.791 us; speedup vs baseline: 2.5108x; 2.2883x over previous
//
#include <hip/hip_runtime.h>

#define DD 128
#define NP 8
#define NK 4
#define NB 65536
#define COLS 64      // batch columns per block (both kernels)
#define PSTR 37      // odd stride for 36-float partial rows (conflict-free)
#define CST 136      // c_lds row stride in bf16: 272B = 17*16 -> b128-aligned

typedef __bf16 bf16x8 __attribute__((ext_vector_type(8)));
typedef float  f32x4  __attribute__((ext_vector_type(4)));

// ---------------------------------------------------------------------------
// K1 (verbatim from the passing R2 kernel): attention weights + weighted
// combine + relu + +q + LN1 stats. 256 threads = 64 columns x 4 d-quarters
// (quarter == wave). Dot-product partials reduced across waves via padded LDS.
// Writes y to d_out, (mu, rstd) to ws.
// ---------------------------------------------------------------------------
__global__ __launch_bounds__(256) void k1_attn_combine(
    const float* __restrict__ q, const float* __restrict__ keys,
    const float* __restrict__ A, float* __restrict__ y,
    float* __restrict__ mu_o, float* __restrict__ rs_o)
{
    __shared__ float lds[4 * COLS * PSTR];   // 37888 B
    const int col = threadIdx.x & 63;
    const int dg  = __builtin_amdgcn_readfirstlane(threadIdx.x >> 6); // wave id
    const int b   = blockIdx.x * COLS + col;
    const int dbase = dg * 32;

    // ---- pass 1: partial dots over this wave's 32 d's --------------------
    float qd[NK] = {0.f, 0.f, 0.f, 0.f};
    float kd[NP][NK];
    #pragma unroll
    for (int n = 0; n < NP; ++n)
        #pragma unroll
        for (int k = 0; k < NK; ++k) kd[n][k] = 0.f;

    #pragma unroll 4
    for (int dd = 0; dd < 32; ++dd) {
        const int d = dbase + dd;                       // wave-uniform
        const float4 at = *(const float4*)(A + d * NK);        // s_load
        const float4 ab = *(const float4*)(A + (DD + d) * NK); // s_load
        const float qv = q[d * NB + b];
        qd[0] += qv * at.x; qd[1] += qv * at.y;
        qd[2] += qv * at.z; qd[3] += qv * at.w;
        #pragma unroll
        for (int n = 0; n < NP; ++n) {
            const float kv = keys[(n * DD + d) * NB + b];
            kd[n][0] += kv * ab.x; kd[n][1] += kv * ab.y;
            kd[n][2] += kv * ab.z; kd[n][3] += kv * ab.w;
        }
    }

    // ---- cross-wave reduce of the 36 partials ----------------------------
    {
        float* my = &lds[(dg * COLS + col) * PSTR];
        #pragma unroll
        for (int k = 0; k < NK; ++k) my[k] = qd[k];
        #pragma unroll
        for (int n = 0; n < NP; ++n)
            #pragma unroll
            for (int k = 0; k < NK; ++k) my[4 + n * NK + k] = kd[n][k];
    }
    __syncthreads();
    #pragma unroll
    for (int ii = 0; ii < 9; ++ii) {
        const int i = dg * 9 + ii;
        float s = lds[(0 * COLS + col) * PSTR + i]
                + lds[(1 * COLS + col) * PSTR + i]
                + lds[(2 * COLS + col) * PSTR + i]
                + lds[(3 * COLS + col) * PSTR + i];
        lds[col * PSTR + i] = s;   // self-RAW only: safe
    }
    __syncthreads();

    // ---- softmax over n ---------------------------------------------------
    float z[NP][NK];
    {
        float qs[NK];
        #pragma unroll
        for (int k = 0; k < NK; ++k) qs[k] = lds[col * PSTR + k];
        float mx[NK] = {-3.4e38f, -3.4e38f, -3.4e38f, -3.4e38f};
        #pragma unroll
        for (int n = 0; n < NP; ++n)
            #pragma unroll
            for (int k = 0; k < NK; ++k) {
                float v = qs[k] + lds[col * PSTR + 4 + n * NK + k];
                v = (v >= 0.f) ? v : 0.01f * v;     // leaky_relu
                z[n][k] = v;
                mx[k] = fmaxf(mx[k], v);
            }
        float S[NK] = {0.f, 0.f, 0.f, 0.f};
        #pragma unroll
        for (int n = 0; n < NP; ++n)
            #pragma unroll
            for (int k = 0; k < NK; ++k) {
                const float e = __expf(z[n][k] - mx[k]);
                z[n][k] = e;
                S[k] += e;
            }
        #pragma unroll
        for (int k = 0; k < NK; ++k) S[k] = 1.f / S[k];
        #pragma unroll
        for (int n = 0; n < NP; ++n)
            z[n][0] = 0.25f * (z[n][0] * S[0] + z[n][1] * S[1] +
                               z[n][2] * S[2] + z[n][3] * S[3]);
    }
    float w[NP];
    #pragma unroll
    for (int n = 0; n < NP; ++n) w[n] = z[n][0];
    __syncthreads();   // protect lds before stats reuse

    // ---- pass 2: weighted combine + relu + residual + LN1 partials -------
    float sum = 0.f, ssq = 0.f;
    #pragma unroll 4
    for (int dd = 0; dd < 32; ++dd) {
        const int d = dbase + dd;
        float acc = 0.f;
        #pragma unroll
        for (int n = 0; n < NP; ++n) acc += w[n] * keys[(n * DD + d) * NB + b];
        const float yv = fmaxf(acc, 0.f) + q[d * NB + b];
        y[d * NB + b] = yv;
        sum += yv;
        ssq += yv * yv;
    }
    lds[(dg * COLS + col) * PSTR + 0] = sum;
    lds[(dg * COLS + col) * PSTR + 1] = ssq;
    __syncthreads();
    if (dg == 0) {
        float ts = 0.f, tq = 0.f;
        #pragma unroll
        for (int g = 0; g < 4; ++g) {
            ts += lds[(g * COLS + col) * PSTR + 0];
            tq += lds[(g * COLS + col) * PSTR + 1];
        }
        const float mu  = ts * (1.f / DD);
        const float var = tq * (1.f / DD) - mu * mu;
        mu_o[b] = mu;
        rs_o[b] = rsqrtf(var + 1e-6f);
    }
}

// ---------------------------------------------------------------------------
// K2: c = LN1(y) -> bf16 LDS tile; bf16 MFMA W@c; +B +c; LN2; store.
// MFMA/epilogue structure is the R3-verified one (wave wv owns 32 rows,
// all 64 block columns; c16 = lane&15, dg = lane>>4). In-place over d_out:
// all y reads precede barrier 1, out writes follow barrier 2, blocks own
// disjoint columns.
// ---------------------------------------------------------------------------
__global__ __launch_bounds__(256, 3) void k2_mfma(
    const float* y, const float* __restrict__ mu_a, const float* __restrict__ rs_a,
    const float* __restrict__ g1, const float* __restrict__ b1,
    const float* __restrict__ W,  const float* __restrict__ Bv,
    const float* __restrict__ g2, const float* __restrict__ b2,
    float* out)
{
    __shared__ __align__(16) __bf16 c_l[COLS * CST];    // 17408 B
    __shared__ float sums2[4][COLS][2];                 // 2048 B

    const int t    = threadIdx.x;
    const int col  = t & 63;
    const int qtr  = t >> 6;            // wave id 0..3
    const int gcol0 = blockIdx.x * COLS;
    const int b    = gcol0 + col;
    const float mu = mu_a[b], rs = rs_a[b];

    // ---- build c tile: thread = (col, d-quarter); 256B-coalesced y loads --
    {
        bf16x8 cb[4];
        #pragma unroll
        for (int j = 0; j < 4; ++j)
            #pragma unroll
            for (int e = 0; e < 8; ++e) {
                const int d = qtr * 32 + j * 8 + e;     // wave-uniform
                cb[j][e] = (__bf16)(g1[d] * ((y[d * NB + b] - mu) * rs) + b1[d]);
            }
        #pragma unroll
        for (int j = 0; j < 4; ++j)
            *(bf16x8*)(c_l + col * CST + qtr * 32 + j * 8) = cb[j];
    }
    __syncthreads();   // (1) c tile complete

    // ---- MFMA: wave qtr -> rows qtr*32..+31, cols 0..63 (R3-verified) ----
    const int lane = t & 63;
    const int c16  = lane & 15;
    const int dg   = lane >> 4;

    bf16x8 wf[2][4];
    #pragma unroll
    for (int mi = 0; mi < 2; ++mi)
        #pragma unroll
        for (int kk = 0; kk < 4; ++kk) {
            const int row = qtr * 32 + mi * 16 + c16;
            const int kb  = kk * 32 + dg * 8;
            const float4 wa = *(const float4*)(W + row * DD + kb);
            const float4 wb = *(const float4*)(W + row * DD + kb + 4);
            bf16x8 f;
            f[0] = (__bf16)wa.x; f[1] = (__bf16)wa.y;
            f[2] = (__bf16)wa.z; f[3] = (__bf16)wa.w;
            f[4] = (__bf16)wb.x; f[5] = (__bf16)wb.y;
            f[6] = (__bf16)wb.z; f[7] = (__bf16)wb.w;
            wf[mi][kk] = f;
        }

    f32x4 acc[2][4];
    #pragma unroll
    for (int mi = 0; mi < 2; ++mi)
        #pragma unroll
        for (int nf = 0; nf < 4; ++nf)
            acc[mi][nf] = (f32x4){0.f, 0.f, 0.f, 0.f};

    #pragma unroll
    for (int kk = 0; kk < 4; ++kk) {
        bf16x8 bfv[4];
        #pragma unroll
        for (int nf = 0; nf < 4; ++nf)
            bfv[nf] = *(const bf16x8*)(c_l + (nf * 16 + c16) * CST + kk * 32 + dg * 8);
        #pragma unroll
        for (int mi = 0; mi < 2; ++mi)
            #pragma unroll
            for (int nf = 0; nf < 4; ++nf)
                acc[mi][nf] = __builtin_amdgcn_mfma_f32_16x16x32_bf16(
                    wf[mi][kk], bfv[nf], acc[mi][nf], 0, 0, 0);
    }

    // ---- epilogue: +B +c, LN2 over 4 waves, store (R3-verified) ----------
    float Brow[2][4], grow[2][4], brow[2][4];
    #pragma unroll
    for (int mi = 0; mi < 2; ++mi)
        #pragma unroll
        for (int r = 0; r < 4; ++r) {
            const int row = qtr * 32 + mi * 16 + dg * 4 + r;
            Brow[mi][r] = Bv[row];
            grow[mi][r] = g2[row];
            brow[mi][r] = b2[row];
        }

    float vv[2][4][4];
    float ps[4] = {0.f,0.f,0.f,0.f}, pq[4] = {0.f,0.f,0.f,0.f};
    #pragma unroll
    for (int nf = 0; nf < 4; ++nf) {
        const int cl = nf * 16 + c16;
        #pragma unroll
        for (int mi = 0; mi < 2; ++mi)
            #pragma unroll
            for (int r = 0; r < 4; ++r) {
                const int row = qtr * 32 + mi * 16 + dg * 4 + r;
                const float cres = (float)c_l[cl * CST + row];
                const float v = acc[mi][nf][r] + Brow[mi][r] + cres;
                vv[mi][nf][r] = v;
                ps[nf] += v;
                pq[nf] += v * v;
            }
    }
    #pragma unroll
    for (int nf = 0; nf < 4; ++nf) {
        ps[nf] += __shfl_xor(ps[nf], 16); ps[nf] += __shfl_xor(ps[nf], 32);
        pq[nf] += __shfl_xor(pq[nf], 16); pq[nf] += __shfl_xor(pq[nf], 32);
    }
    if (dg == 0) {
        #pragma unroll
        for (int nf = 0; nf < 4; ++nf) {
            sums2[qtr][nf * 16 + c16][0] = ps[nf];
            sums2[qtr][nf * 16 + c16][1] = pq[nf];
        }
    }
    __syncthreads();   // (2) LN2 cross-wave sums ready

    #pragma unroll
    for (int nf = 0; nf < 4; ++nf) {
        const int cl = nf * 16 + c16;
        float ts = 0.f, tq = 0.f;
        #pragma unroll
        for (int g = 0; g < 4; ++g) {
            ts += sums2[g][cl][0];
            tq += sums2[g][cl][1];
        }
        const float mu2 = ts * (1.f / DD);
        const float rs2 = rsqrtf(tq * (1.f / DD) - mu2 * mu2 + 1e-6f);
        #pragma unroll
        for (int mi = 0; mi < 2; ++mi)
            #pragma unroll
            for (int r = 0; r < 4; ++r) {
                const int row = qtr * 32 + mi * 16 + dg * 4 + r;
                out[row * NB + gcol0 + cl] =
                    grow[mi][r] * ((vv[mi][nf][r] - mu2) * rs2) + brow[mi][r];
            }
    }
}

extern "C" void kernel_launch(void* const* d_in, const int* in_sizes, int n_in,
                              void* d_out, int out_size, void* d_ws, size_t ws_size,
                              hipStream_t stream)
{
    const float* q    = (const float*)d_in[0];  // [1,128,65536]
    const float* keys = (const float*)d_in[1];  // [8,128,65536]
    const float* A    = (const float*)d_in[2];  // [256,4]
    const float* g1   = (const float*)d_in[3];
    const float* b1   = (const float*)d_in[4];
    const float* W    = (const float*)d_in[5];  // [128,128]
    const float* Bv   = (const float*)d_in[6];  // [128,1]
    const float* g2   = (const float*)d_in[7];
    const float* b2   = (const float*)d_in[8];
    float* out = (float*)d_out;                 // [128,65536]

    float* mu = (float*)d_ws;                   // [65536]
    float* rs = mu + NB;                        // [65536]

    k1_attn_combine<<<NB / COLS, 256, 0, stream>>>(q, keys, A, out, mu, rs);
    k2_mfma<<<NB / COLS, 256, 0, stream>>>(out, mu, rs, g1, b1, W, Bv, g2, b2, out);
}

// Round 7
// 114.837 us; speedup vs baseline: 2.6629x; 1.0606x over previous
//
#include <hip/hip_runtime.h>

#define DD 128
#define NP 8
#define NK 4
#define NB 65536
#define COLS 64      // batch columns per block
#define PSTR 37      // odd stride for 36-float partial rows (conflict-free)
#define CST 136      // c_l row stride in bf16: 272B = 17*16 -> b128-aligned

typedef __bf16 bf16x8 __attribute__((ext_vector_type(8)));
typedef float  f32x4  __attribute__((ext_vector_type(4)));

// ---------------------------------------------------------------------------
// Fully fused: attention weights -> combine -> LN1 -> bf16 c tile -> MFMA
// W@c -> +B +c -> LN2 -> out.  All component layouts are byte-identical to
// the R6-verified two-kernel version (k1 streaming/reduction/softmax; k2
// c-build/MFMA/epilogue).  y never touches global; mu/rs never materialize.
//
// LDS lifetime plan (single 37888B buffer, barrier-separated):
//   phase A (pass1 reduce+softmax): floats [0 .. 9472)    partials/reduced
//   phase B (LN1 stats exchange):   bytes  [18432..20480) sred[4][64][2]
//   phase C (c tile, bf16):         bytes  [0 .. 17408)   c_l[64][CST]
//   phase D (LN2 sums):             bytes  [20480..22528) sums2[4][64][2]
// ---------------------------------------------------------------------------
__global__ __launch_bounds__(256, 4) void fused_all(
    const float* __restrict__ q, const float* __restrict__ keys,
    const float* __restrict__ A,
    const float* __restrict__ g1, const float* __restrict__ b1,
    const float* __restrict__ W,  const float* __restrict__ Bv,
    const float* __restrict__ g2, const float* __restrict__ b2,
    float* __restrict__ out)
{
    __shared__ __align__(16) float lds[4 * COLS * PSTR];   // 37888 B
    __bf16* c_l        = (__bf16*)lds;                      // bytes 0..17407
    float (*sred)[COLS][2]  = (float (*)[COLS][2])((char*)lds + 18432);
    float (*sums2)[COLS][2] = (float (*)[COLS][2])((char*)lds + 20480);

    const int t   = threadIdx.x;
    const int col = t & 63;
    const int dg  = __builtin_amdgcn_readfirstlane(t >> 6);  // wave id 0..3
    const int gcol0 = blockIdx.x * COLS;
    const int b   = gcol0 + col;
    const int dbase = dg * 32;

    // ---- pass 1: partial dots over this wave's 32 d's (R6-k1 verbatim) ---
    float qd[NK] = {0.f, 0.f, 0.f, 0.f};
    float kd[NP][NK];
    #pragma unroll
    for (int n = 0; n < NP; ++n)
        #pragma unroll
        for (int k = 0; k < NK; ++k) kd[n][k] = 0.f;

    #pragma unroll 4
    for (int dd = 0; dd < 32; ++dd) {
        const int d = dbase + dd;                       // wave-uniform
        const float4 at = *(const float4*)(A + d * NK);        // s_load
        const float4 ab = *(const float4*)(A + (DD + d) * NK); // s_load
        const float qv = q[d * NB + b];
        qd[0] += qv * at.x; qd[1] += qv * at.y;
        qd[2] += qv * at.z; qd[3] += qv * at.w;
        #pragma unroll
        for (int n = 0; n < NP; ++n) {
            const float kv = keys[(n * DD + d) * NB + b];
            kd[n][0] += kv * ab.x; kd[n][1] += kv * ab.y;
            kd[n][2] += kv * ab.z; kd[n][3] += kv * ab.w;
        }
    }

    // ---- cross-wave reduce of the 36 partials (R6-k1 verbatim) -----------
    {
        float* my = &lds[(dg * COLS + col) * PSTR];
        #pragma unroll
        for (int k = 0; k < NK; ++k) my[k] = qd[k];
        #pragma unroll
        for (int n = 0; n < NP; ++n)
            #pragma unroll
            for (int k = 0; k < NK; ++k) my[4 + n * NK + k] = kd[n][k];
    }
    __syncthreads();                                    // (1)
    #pragma unroll
    for (int ii = 0; ii < 9; ++ii) {
        const int i = dg * 9 + ii;
        float s = lds[(0 * COLS + col) * PSTR + i]
                + lds[(1 * COLS + col) * PSTR + i]
                + lds[(2 * COLS + col) * PSTR + i]
                + lds[(3 * COLS + col) * PSTR + i];
        lds[col * PSTR + i] = s;   // self-RAW only: safe
    }
    __syncthreads();                                    // (2)

    // ---- softmax over n (R6-k1 verbatim) ---------------------------------
    float w[NP];
    {
        float z[NP][NK];
        float qs[NK];
        #pragma unroll
        for (int k = 0; k < NK; ++k) qs[k] = lds[col * PSTR + k];
        float mx[NK] = {-3.4e38f, -3.4e38f, -3.4e38f, -3.4e38f};
        #pragma unroll
        for (int n = 0; n < NP; ++n)
            #pragma unroll
            for (int k = 0; k < NK; ++k) {
                float v = qs[k] + lds[col * PSTR + 4 + n * NK + k];
                v = (v >= 0.f) ? v : 0.01f * v;     // leaky_relu
                z[n][k] = v;
                mx[k] = fmaxf(mx[k], v);
            }
        float S[NK] = {0.f, 0.f, 0.f, 0.f};
        #pragma unroll
        for (int n = 0; n < NP; ++n)
            #pragma unroll
            for (int k = 0; k < NK; ++k) {
                const float e = __expf(z[n][k] - mx[k]);
                z[n][k] = e;
                S[k] += e;
            }
        #pragma unroll
        for (int k = 0; k < NK; ++k) S[k] = 1.f / S[k];
        #pragma unroll
        for (int n = 0; n < NP; ++n)
            w[n] = 0.25f * (z[n][0] * S[0] + z[n][1] * S[1] +
                            z[n][2] * S[2] + z[n][3] * S[3]);
    }

    // ---- pass 2: weighted combine + relu + +q; y stays in registers ------
    float y[32];
    float sum = 0.f, ssq = 0.f;
    #pragma unroll 4
    for (int dd = 0; dd < 32; ++dd) {
        const int d = dbase + dd;
        float acc = 0.f;
        #pragma unroll
        for (int n = 0; n < NP; ++n) acc += w[n] * keys[(n * DD + d) * NB + b];
        const float yv = fmaxf(acc, 0.f) + q[d * NB + b];
        y[dd] = yv;
        sum += yv;
        ssq += yv * yv;
    }
    __syncthreads();   // (3) all softmax reads of lds[0..9472) are done
    sred[dg][col][0] = sum;
    sred[dg][col][1] = ssq;
    __syncthreads();   // (4) stats ready
    float ts1 = 0.f, tq1 = 0.f;
    #pragma unroll
    for (int g = 0; g < 4; ++g) {
        ts1 += sred[g][col][0];
        tq1 += sred[g][col][1];
    }
    const float mu = ts1 * (1.f / DD);
    const float rs = rsqrtf(tq1 * (1.f / DD) - mu * mu + 1e-6f);

    // ---- c = LN1(y) -> bf16 -> c_l tile (R6-k2 layout, y from regs) ------
    {
        bf16x8 cb[4];
        #pragma unroll
        for (int j = 0; j < 4; ++j)
            #pragma unroll
            for (int e = 0; e < 8; ++e) {
                const int d = dbase + j * 8 + e;        // wave-uniform
                cb[j][e] = (__bf16)(g1[d] * ((y[j * 8 + e] - mu) * rs) + b1[d]);
            }
        #pragma unroll
        for (int j = 0; j < 4; ++j)
            *(bf16x8*)(c_l + col * CST + dbase + j * 8) = cb[j];
    }
    __syncthreads();   // (5) c tile complete

    // ---- MFMA: wave dg -> rows dg*32..+31, cols 0..63 (R6-k2 verbatim) ---
    const int lane = t & 63;
    const int c16  = lane & 15;
    const int dg4  = lane >> 4;

    bf16x8 wf[2][4];
    #pragma unroll
    for (int mi = 0; mi < 2; ++mi)
        #pragma unroll
        for (int kk = 0; kk < 4; ++kk) {
            const int row = dg * 32 + mi * 16 + c16;
            const int kb  = kk * 32 + dg4 * 8;
            const float4 wa = *(const float4*)(W + row * DD + kb);
            const float4 wb = *(const float4*)(W + row * DD + kb + 4);
            bf16x8 f;
            f[0] = (__bf16)wa.x; f[1] = (__bf16)wa.y;
            f[2] = (__bf16)wa.z; f[3] = (__bf16)wa.w;
            f[4] = (__bf16)wb.x; f[5] = (__bf16)wb.y;
            f[6] = (__bf16)wb.z; f[7] = (__bf16)wb.w;
            wf[mi][kk] = f;
        }

    f32x4 acc[2][4];
    #pragma unroll
    for (int mi = 0; mi < 2; ++mi)
        #pragma unroll
        for (int nf = 0; nf < 4; ++nf)
            acc[mi][nf] = (f32x4){0.f, 0.f, 0.f, 0.f};

    #pragma unroll
    for (int kk = 0; kk < 4; ++kk) {
        bf16x8 bfv[4];
        #pragma unroll
        for (int nf = 0; nf < 4; ++nf)
            bfv[nf] = *(const bf16x8*)(c_l + (nf * 16 + c16) * CST + kk * 32 + dg4 * 8);
        #pragma unroll
        for (int mi = 0; mi < 2; ++mi)
            #pragma unroll
            for (int nf = 0; nf < 4; ++nf)
                acc[mi][nf] = __builtin_amdgcn_mfma_f32_16x16x32_bf16(
                    wf[mi][kk], bfv[nf], acc[mi][nf], 0, 0, 0);
    }

    // ---- epilogue: +B +c, LN2 over 4 waves, store (R6-k2 verbatim) -------
    float Brow[2][4], grow[2][4], brow[2][4];
    #pragma unroll
    for (int mi = 0; mi < 2; ++mi)
        #pragma unroll
        for (int r = 0; r < 4; ++r) {
            const int row = dg * 32 + mi * 16 + dg4 * 4 + r;
            Brow[mi][r] = Bv[row];
            grow[mi][r] = g2[row];
            brow[mi][r] = b2[row];
        }

    float vv[2][4][4];
    float ps[4] = {0.f,0.f,0.f,0.f}, pq[4] = {0.f,0.f,0.f,0.f};
    #pragma unroll
    for (int nf = 0; nf < 4; ++nf) {
        const int cl = nf * 16 + c16;
        #pragma unroll
        for (int mi = 0; mi < 2; ++mi)
            #pragma unroll
            for (int r = 0; r < 4; ++r) {
                const int row = dg * 32 + mi * 16 + dg4 * 4 + r;
                const float cres = (float)c_l[cl * CST + row];
                const float v = acc[mi][nf][r] + Brow[mi][r] + cres;
                vv[mi][nf][r] = v;
                ps[nf] += v;
                pq[nf] += v * v;
            }
    }
    #pragma unroll
    for (int nf = 0; nf < 4; ++nf) {
        ps[nf] += __shfl_xor(ps[nf], 16); ps[nf] += __shfl_xor(ps[nf], 32);
        pq[nf] += __shfl_xor(pq[nf], 16); pq[nf] += __shfl_xor(pq[nf], 32);
    }
    if (dg4 == 0) {
        #pragma unroll
        for (int nf = 0; nf < 4; ++nf) {
            sums2[dg][nf * 16 + c16][0] = ps[nf];
            sums2[dg][nf * 16 + c16][1] = pq[nf];
        }
    }
    __syncthreads();   // (6) LN2 cross-wave sums ready

    #pragma unroll
    for (int nf = 0; nf < 4; ++nf) {
        const int cl = nf * 16 + c16;
        float ts = 0.f, tq = 0.f;
        #pragma unroll
        for (int g = 0; g < 4; ++g) {
            ts += sums2[g][cl][0];
            tq += sums2[g][cl][1];
        }
        const float mu2 = ts * (1.f / DD);
        const float rs2 = rsqrtf(tq * (1.f / DD) - mu2 * mu2 + 1e-6f);
        #pragma unroll
        for (int mi = 0; mi < 2; ++mi)
            #pragma unroll
            for (int r = 0; r < 4; ++r) {
                const int row = dg * 32 + mi * 16 + dg4 * 4 + r;
                out[row * NB + gcol0 + cl] =
                    grow[mi][r] * ((vv[mi][nf][r] - mu2) * rs2) + brow[mi][r];
            }
    }
}

extern "C" void kernel_launch(void* const* d_in, const int* in_sizes, int n_in,
                              void* d_out, int out_size, void* d_ws, size_t ws_size,
                              hipStream_t stream)
{
    const float* q    = (const float*)d_in[0];  // [1,128,65536]
    const float* keys = (const float*)d_in[1];  // [8,128,65536]
    const float* A    = (const float*)d_in[2];  // [256,4]
    const float* g1   = (const float*)d_in[3];
    const float* b1   = (const float*)d_in[4];
    const float* W    = (const float*)d_in[5];  // [128,128]
    const float* Bv   = (const float*)d_in[6];  // [128,1]
    const float* g2   = (const float*)d_in[7];
    const float* b2   = (const float*)d_in[8];
    float* out = (float*)d_out;                 // [128,65536]

    fused_all<<<NB / COLS, 256, 0, stream>>>(q, keys, A, g1, b1, W, Bv, g2, b2, out);
}